// Round 2
// baseline (766.124 us; speedup 1.0000x reference)
//
#include <hip/hip_runtime.h>

typedef __bf16 bf16;
typedef __attribute__((ext_vector_type(8))) __bf16 bf16x8;
typedef __attribute__((ext_vector_type(4))) float f32x4;
typedef __attribute__((ext_vector_type(4))) unsigned short u16x4;
typedef __attribute__((ext_vector_type(8))) unsigned short u16x8;
typedef __attribute__((ext_vector_type(4))) float float4v;

#define MFMA16(a,b,c) __builtin_amdgcn_mfma_f32_16x16x32_bf16((a),(b),(c),0,0,0)

// Problem dims: B=8, C=768, H=W=64, S=4096, CK=96, L=CK*H=6144, D=W=64
// Workspace layout (bytes):
static constexpr size_t OFF_WQKV = 0;                                   // [288][768] bf16
static constexpr size_t OFF_WC   = OFF_WQKV + (size_t)288*768*2;        // [768][96] bf16
static constexpr size_t OFF_QKV  = OFF_WC   + (size_t)768*96*2;         // [8][288][4096] bf16
static constexpr size_t OFF_A    = OFF_QKV  + (size_t)8*288*4096*2;     // [8][96][4096] bf16
static constexpr size_t OFF_AT   = OFF_A    + (size_t)8*96*4096*2;      // shared: Vt[8][64][6144] then At[8][4096][96]
// total ~32.1 MB

// ---------------- k0: convert weights to bf16 ----------------
__global__ __launch_bounds__(256) void k_wcvt(const float* __restrict__ Wq,
                                              const float* __restrict__ Wk,
                                              const float* __restrict__ Wv,
                                              const float* __restrict__ Wc,
                                              bf16* __restrict__ Wqkv,
                                              bf16* __restrict__ Wcb) {
  int t = blockIdx.x * 256 + threadIdx.x;
  int base = t * 4;
  float4v v;
  if (base < 73728)        v = ((const float4v*)Wq)[t];
  else if (base < 147456)  v = ((const float4v*)Wk)[t - 18432];
  else if (base < 221184)  v = ((const float4v*)Wv)[t - 36864];
  else                     v = ((const float4v*)Wc)[t - 55296];
  u16x4 o;
  #pragma unroll
  for (int i = 0; i < 4; ++i) {
    bf16 h = (bf16)v[i];
    o[i] = __builtin_bit_cast(unsigned short, h);
  }
  if (base < 221184) ((u16x4*)Wqkv)[t] = o;
  else               ((u16x4*)Wcb)[t - 55296] = o;
}

// ---------------- k1: fused QKV projection ----------------
__global__ __launch_bounds__(384) void k_proj(const float* __restrict__ x,
                                              const bf16* __restrict__ Wqkv,
                                              bf16* __restrict__ QKV) {
  __shared__ __align__(16) unsigned char ldsT[64 * 256];
  const int t = threadIdx.x, wid = t >> 6, l = t & 63;
  const int b = blockIdx.y, s0 = blockIdx.x * 64;
  const int lq = l >> 4, lr = l & 15;
  f32x4 acc[3][4] = {};
  for (int ch = 0; ch < 8; ++ch) {
    const int cbase = ch * 96;
    #pragma unroll
    for (int it = 0; it < 2; ++it) {
      int c0 = wid * 8 + it * 48;
      bf16x8 pk;
      #pragma unroll
      for (int j = 0; j < 8; ++j)
        pk[j] = (bf16)x[(size_t)(b * 768 + cbase + c0 + j) * 4096 + s0 + l];
      *(bf16x8*)(ldsT + ((l * 256 + c0 * 2) ^ ((l & 7) << 4))) = pk;
    }
    __syncthreads();
    #pragma unroll
    for (int kk = 0; kk < 3; ++kk) {
      bf16x8 af[3], bv[4];
      #pragma unroll
      for (int ma = 0; ma < 3; ++ma) {
        int row = wid * 48 + ma * 16 + lr;
        af[ma] = *(const bf16x8*)&Wqkv[(size_t)row * 768 + cbase + kk * 32 + lq * 8];
      }
      #pragma unroll
      for (int nb = 0; nb < 4; ++nb) {
        int sl = nb * 16 + lr;
        bv[nb] = *(const bf16x8*)(ldsT + ((sl * 256 + (kk * 32 + lq * 8) * 2) ^ ((sl & 7) << 4)));
      }
      #pragma unroll
      for (int ma = 0; ma < 3; ++ma)
        #pragma unroll
        for (int nb = 0; nb < 4; ++nb)
          acc[ma][nb] = MFMA16(af[ma], bv[nb], acc[ma][nb]);
    }
    __syncthreads();
  }
  #pragma unroll
  for (int ma = 0; ma < 3; ++ma)
    #pragma unroll
    for (int nb = 0; nb < 4; ++nb)
      #pragma unroll
      for (int i = 0; i < 4; ++i) {
        int o3 = wid * 48 + ma * 16 + lq * 4 + i;
        int s  = s0 + nb * 16 + lr;
        QKV[((size_t)b * 288 + o3) * 4096 + s] = (bf16)acc[ma][nb][i];
      }
}

// ---------------- k1b: transpose V -> Vt[b][64 w][6144 l] ----------------
__global__ __launch_bounds__(256) void k_vt(const bf16* __restrict__ QKV,
                                            bf16* __restrict__ Vt) {
  __shared__ __align__(16) unsigned char T[64 * 128];
  const int t = threadIdx.x;
  const int b = blockIdx.y, ck = blockIdx.x;
  const bf16* Vb = QKV + (size_t)b * 288 * 4096 + (size_t)192 * 4096 + (size_t)ck * 4096;
  #pragma unroll
  for (int it = 0; it < 2; ++it) {
    int h = (t >> 3) + it * 32;
    int c8 = t & 7;
    u16x8 v = *(const u16x8*)&Vb[h * 64 + c8 * 8];
    *(u16x8*)(T + ((h * 128 + c8 * 16) ^ ((h & 7) << 4))) = v;
  }
  __syncthreads();
  const int w = t & 63, hs = t >> 6;
  u16x8 o0, o1;
  #pragma unroll
  for (int e = 0; e < 8; ++e) {
    int h = hs * 16 + e;
    o0[e] = *(const unsigned short*)(T + ((h * 128 + w * 2) ^ ((h & 7) << 4)));
  }
  #pragma unroll
  for (int e = 0; e < 8; ++e) {
    int h = hs * 16 + 8 + e;
    o1[e] = *(const unsigned short*)(T + ((h * 128 + w * 2) ^ ((h & 7) << 4)));
  }
  bf16* dst = Vt + (size_t)b * 64 * 6144 + (size_t)w * 6144 + ck * 64 + hs * 16;
  *(u16x8*)(dst) = o0;
  *(u16x8*)(dst + 8) = o1;
}

// ---------------- k2: flash attention, barrier-free ----------------
// grid (96,8), 4 waves x 16 q-rows. K + V^T direct from global (L2-served),
// K register-pipelined one tile ahead; P via per-wave LDS in exact A-frag order.
__global__ __launch_bounds__(256, 3) void k_attn(const bf16* __restrict__ QKV,
                                                 const bf16* __restrict__ Vt,
                                                 bf16* __restrict__ A) {
  __shared__ __align__(16) unsigned char Pl[4][2048];   // [kk][lane][16B] per wave
  const int t = threadIdx.x, wid = t >> 6, l = t & 63;
  const int b = blockIdx.y, qb = blockIdx.x;
  const int lq = l >> 4, lr = l & 15;
  const bf16* Qb  = QKV + (size_t)b * 288 * 4096;
  const bf16* Kb  = Qb + (size_t)96 * 4096;
  const bf16* Vtb = Vt + (size_t)b * 64 * 6144;
  const int qr = qb * 64 + wid * 16 + lr;
  bf16x8 qf[2];
  qf[0] = *(const bf16x8*)&Qb[(size_t)qr * 64 + lq * 8];
  qf[1] = *(const bf16x8*)&Qb[(size_t)qr * 64 + 32 + lq * 8];
  f32x4 oacc[4] = {};
  float m2 = -INFINITY, lsum = 0.f;
  const float LOG2E = 1.44269504f;
  unsigned char* Pw = Pl[wid];
  const int pwb = lr * 16 + (lq & 1) * 8 + (lq >> 1) * 256;  // P write base (A-frag order)
  bf16x8 kf[8], vf[8];
  #pragma unroll
  for (int kb = 0; kb < 4; ++kb)
    #pragma unroll
    for (int kk = 0; kk < 2; ++kk)
      kf[kb * 2 + kk] = *(const bf16x8*)&Kb[(size_t)(kb * 16 + lr) * 64 + kk * 32 + lq * 8];

  for (int kt = 0; kt < 96; ++kt) {
    // QK^T (S^T): lane -> q-row lr, kcols kb*16 + lq*4 + i
    f32x4 st[4] = {};
    #pragma unroll
    for (int kb = 0; kb < 4; ++kb)
      #pragma unroll
      for (int kk = 0; kk < 2; ++kk)
        st[kb] = MFMA16(kf[kb * 2 + kk], qf[kk], st[kb]);
    // issue V(kt) loads, then prefetch K(kt+1) into the (now dead) kf regs
    #pragma unroll
    for (int wb = 0; wb < 4; ++wb)
      #pragma unroll
      for (int kk = 0; kk < 2; ++kk)
        vf[wb * 2 + kk] = *(const bf16x8*)&Vtb[(size_t)(wb * 16 + lr) * 6144 + kt * 64 + kk * 32 + lq * 8];
    const int ktn = (kt + 1 < 96) ? (kt + 1) : 0;
    #pragma unroll
    for (int kb = 0; kb < 4; ++kb)
      #pragma unroll
      for (int kk = 0; kk < 2; ++kk)
        kf[kb * 2 + kk] = *(const bf16x8*)&Kb[(size_t)(ktn * 64 + kb * 16 + lr) * 64 + kk * 32 + lq * 8];
    // online softmax (base-2)
    float tm = st[0][0];
    #pragma unroll
    for (int kb = 0; kb < 4; ++kb)
      #pragma unroll
      for (int i = 0; i < 4; ++i) tm = fmaxf(tm, st[kb][i]);
    tm = fmaxf(tm, __shfl_xor(tm, 16));
    tm = fmaxf(tm, __shfl_xor(tm, 32));
    float m2n = fmaxf(m2, tm * LOG2E);
    float alpha = exp2f(m2 - m2n);
    float p[16], rs = 0.f;
    #pragma unroll
    for (int kb = 0; kb < 4; ++kb)
      #pragma unroll
      for (int i = 0; i < 4; ++i) {
        float pv = exp2f(fmaf(st[kb][i], LOG2E, -m2n));
        p[kb * 4 + i] = pv; rs += pv;
      }
    rs += __shfl_xor(rs, 16);
    rs += __shfl_xor(rs, 32);
    lsum = lsum * alpha + rs;
    m2 = m2n;
    float al[4];
    #pragma unroll
    for (int i = 0; i < 4; ++i) al[i] = __shfl(alpha, lq * 4 + i);
    #pragma unroll
    for (int wb = 0; wb < 4; ++wb)
      #pragma unroll
      for (int i = 0; i < 4; ++i) oacc[wb][i] *= al[i];
    // write P in A-fragment order: value kcol -> byte (kcol>>5)*1024 + lane'(kcol)*16 + (kcol&7)*2
    #pragma unroll
    for (int kb = 0; kb < 4; ++kb)
      #pragma unroll
      for (int pr = 0; pr < 2; ++pr) {
        bf16 b0 = (bf16)p[kb * 4 + pr * 2], b1 = (bf16)p[kb * 4 + pr * 2 + 1];
        unsigned int u = (unsigned int)__builtin_bit_cast(unsigned short, b0)
                       | ((unsigned int)__builtin_bit_cast(unsigned short, b1) << 16);
        *(unsigned int*)(Pw + pwb + kb * 512 + pr * 4) = u;
      }
    // linear conflict-free read + PV
    #pragma unroll
    for (int kk = 0; kk < 2; ++kk) {
      bf16x8 pa = *(const bf16x8*)(Pw + kk * 1024 + l * 16);
      #pragma unroll
      for (int wb = 0; wb < 4; ++wb)
        oacc[wb] = MFMA16(pa, vf[wb * 2 + kk], oacc[wb]);
    }
  }
  float linv[4];
  #pragma unroll
  for (int i = 0; i < 4; ++i) {
    float li = __shfl(lsum, lq * 4 + i);
    linv[i] = 1.0f / li;
  }
  bf16* Ab = A + (size_t)b * 96 * 4096;
  #pragma unroll
  for (int wb = 0; wb < 4; ++wb)
    #pragma unroll
    for (int i = 0; i < 4; ++i) {
      int row = qb * 64 + wid * 16 + lq * 4 + i;
      Ab[(size_t)row * 64 + wb * 16 + lr] = (bf16)(oacc[wb][i] * linv[i]);
    }
}

// ---------------- k2b: transpose A[b][96][4096] -> At[b][4096][96] ----------------
__global__ __launch_bounds__(256) void k_at(const bf16* __restrict__ A,
                                            bf16* __restrict__ At) {
  __shared__ unsigned char T[96 * 128];
  const int t = threadIdx.x;
  const int b = blockIdx.y, s0 = blockIdx.x * 64;
  #pragma unroll
  for (int it = 0; it < 6; ++it) {
    int c = (t >> 4) + it * 16;
    int s = (t & 15) * 4;
    u16x4 va = *(const u16x4*)&A[((size_t)b * 96 + c) * 4096 + s0 + s];
    #pragma unroll
    for (int pr = 0; pr < 2; ++pr) {
      unsigned int u = (unsigned int)va[pr * 2] | ((unsigned int)va[pr * 2 + 1] << 16);
      int byte = (c * 128 + (s + pr * 2) * 2) ^ ((c & 7) << 2) ^ (((c >> 3) & 3) << 5);
      *(unsigned int*)(T + byte) = u;
    }
  }
  __syncthreads();
  int s = t >> 2, c0 = (t & 3) * 24;
  unsigned short us[24];
  #pragma unroll
  for (int e = 0; e < 24; ++e) {
    int c = c0 + e;
    int byte = (c * 128 + s * 2) ^ ((c & 7) << 2) ^ (((c >> 3) & 3) << 5);
    us[e] = *(const unsigned short*)(T + byte);
  }
  bf16* dst = At + ((size_t)b * 4096 + s0 + s) * 96 + c0;
  #pragma unroll
  for (int v8 = 0; v8 < 3; ++v8) {
    u16x8 o;
    #pragma unroll
    for (int e = 0; e < 8; ++e) o[e] = us[v8 * 8 + e];
    *(u16x8*)(dst + v8 * 8) = o;
  }
}

// ---------------- k3: out = gamma * (Wc @ A) + x ----------------
__global__ __launch_bounds__(256) void k_out(const float* __restrict__ x,
                                             const bf16* __restrict__ Wcb,
                                             const bf16* __restrict__ At,
                                             const float* __restrict__ gamma,
                                             float* __restrict__ out) {
  const int t = threadIdx.x, wid = t >> 6, l = t & 63;
  const int lq = l >> 4, lr = l & 15;
  const int b = blockIdx.z, mb = blockIdx.y, s0 = blockIdx.x * 64;
  f32x4 acc[4][4] = {};
  #pragma unroll
  for (int kk = 0; kk < 3; ++kk) {
    bf16x8 af[4], bv[4];
    #pragma unroll
    for (int ma = 0; ma < 4; ++ma) {
      int row = mb * 256 + wid * 64 + ma * 16 + lr;
      af[ma] = *(const bf16x8*)&Wcb[(size_t)row * 96 + kk * 32 + lq * 8];
    }
    #pragma unroll
    for (int nb = 0; nb < 4; ++nb) {
      int s = s0 + nb * 16 + lr;
      bv[nb] = *(const bf16x8*)&At[((size_t)b * 4096 + s) * 96 + kk * 32 + lq * 8];
    }
    #pragma unroll
    for (int ma = 0; ma < 4; ++ma)
      #pragma unroll
      for (int nb = 0; nb < 4; ++nb)
        acc[ma][nb] = MFMA16(af[ma], bv[nb], acc[ma][nb]);
  }
  float g = gamma[0];
  #pragma unroll
  for (int ma = 0; ma < 4; ++ma)
    #pragma unroll
    for (int nb = 0; nb < 4; ++nb)
      #pragma unroll
      for (int i = 0; i < 4; ++i) {
        int o2 = mb * 256 + wid * 64 + ma * 16 + lq * 4 + i;
        int s  = s0 + nb * 16 + lr;
        size_t idx = ((size_t)b * 768 + o2) * 4096 + s;
        out[idx] = fmaf(acc[ma][nb][i], g, x[idx]);
      }
}

extern "C" void kernel_launch(void* const* d_in, const int* in_sizes, int n_in,
                              void* d_out, int out_size, void* d_ws, size_t ws_size,
                              hipStream_t stream) {
  (void)in_sizes; (void)n_in; (void)out_size; (void)ws_size;
  const float* x     = (const float*)d_in[0];
  const float* Wq    = (const float*)d_in[1];
  const float* Wk    = (const float*)d_in[2];
  const float* Wv    = (const float*)d_in[3];
  const float* Wc    = (const float*)d_in[4];
  const float* gamma = (const float*)d_in[5];
  float* out = (float*)d_out;
  char* ws = (char*)d_ws;
  bf16* Wqkv = (bf16*)(ws + OFF_WQKV);
  bf16* Wcb  = (bf16*)(ws + OFF_WC);
  bf16* QKV  = (bf16*)(ws + OFF_QKV);
  bf16* A    = (bf16*)(ws + OFF_A);
  bf16* VtAt = (bf16*)(ws + OFF_AT);   // Vt during attention, At afterwards

  k_wcvt<<<dim3(288), dim3(256), 0, stream>>>(Wq, Wk, Wv, Wc, Wqkv, Wcb);
  k_proj<<<dim3(64, 8), dim3(384), 0, stream>>>(x, Wqkv, QKV);
  k_vt<<<dim3(96, 8), dim3(256), 0, stream>>>(QKV, VtAt);
  k_attn<<<dim3(96, 8), dim3(256), 0, stream>>>(QKV, VtAt, A);
  k_at<<<dim3(64, 8), dim3(256), 0, stream>>>(A, VtAt);
  k_out<<<dim3(64, 3, 8), dim3(256), 0, stream>>>(x, Wcb, VtAt, gamma, out);
}

// Round 4
// 765.271 us; speedup vs baseline: 1.0011x; 1.0011x over previous
//
#include <hip/hip_runtime.h>

typedef __bf16 bf16;
typedef __attribute__((ext_vector_type(8))) __bf16 bf16x8;
typedef __attribute__((ext_vector_type(4))) float f32x4;
typedef __attribute__((ext_vector_type(4))) unsigned short u16x4;
typedef __attribute__((ext_vector_type(8))) unsigned short u16x8;
typedef __attribute__((ext_vector_type(4))) float float4v;

#define MFMA16(a,b,c) __builtin_amdgcn_mfma_f32_16x16x32_bf16((a),(b),(c),0,0,0)

// Problem dims: B=8, C=768, H=W=64, S=4096, CK=96, L=CK*H=6144, D=W=64
// Workspace layout (bytes), peak 32.1 MB with region reuse:
//   OFF_WQKV: [288][768] bf16 proj weights; dead after k_proj -> reused as Lsum[2][8][6144] f32 (393KB <= 442KB)
//   OFF_WC:   [768][96] bf16 (live to the end)
//   OFF_QKV:  [8][288][4096] bf16.  Per batch: rows 0-95=Q, 96-191=K, 192-287=V.
//             V region dead after k_vt   -> reused as Opart1[b][6144][64] bf16 (exact fit)
//             Q region dead after k_attn -> reused as At[b][4096][96] bf16 (exact fit)
//   OFF_A:    [8][96][4096] bf16 = Opart0[b][6144][64] (same flat layout)
//   OFF_AT:   Vt[8][64][6144] bf16
static constexpr size_t OFF_WQKV = 0;
static constexpr size_t OFF_WC   = OFF_WQKV + (size_t)288*768*2;
static constexpr size_t OFF_QKV  = OFF_WC   + (size_t)768*96*2;
static constexpr size_t OFF_A    = OFF_QKV  + (size_t)8*288*4096*2;
static constexpr size_t OFF_AT   = OFF_A    + (size_t)8*96*4096*2;

// ---------------- k0: convert weights to bf16 ----------------
__global__ __launch_bounds__(256) void k_wcvt(const float* __restrict__ Wq,
                                              const float* __restrict__ Wk,
                                              const float* __restrict__ Wv,
                                              const float* __restrict__ Wc,
                                              bf16* __restrict__ Wqkv,
                                              bf16* __restrict__ Wcb) {
  int t = blockIdx.x * 256 + threadIdx.x;
  int base = t * 4;
  float4v v;
  if (base < 73728)        v = ((const float4v*)Wq)[t];
  else if (base < 147456)  v = ((const float4v*)Wk)[t - 18432];
  else if (base < 221184)  v = ((const float4v*)Wv)[t - 36864];
  else                     v = ((const float4v*)Wc)[t - 55296];
  u16x4 o;
  #pragma unroll
  for (int i = 0; i < 4; ++i) {
    bf16 h = (bf16)v[i];
    o[i] = __builtin_bit_cast(unsigned short, h);
  }
  if (base < 221184) ((u16x4*)Wqkv)[t] = o;
  else               ((u16x4*)Wcb)[t - 55296] = o;
}

// ---------------- k1: fused QKV projection ----------------
__global__ __launch_bounds__(384) void k_proj(const float* __restrict__ x,
                                              const bf16* __restrict__ Wqkv,
                                              bf16* __restrict__ QKV) {
  __shared__ __align__(16) unsigned char ldsT[64 * 256];
  const int t = threadIdx.x, wid = t >> 6, l = t & 63;
  const int b = blockIdx.y, s0 = blockIdx.x * 64;
  const int lq = l >> 4, lr = l & 15;
  f32x4 acc[3][4] = {};
  for (int ch = 0; ch < 8; ++ch) {
    const int cbase = ch * 96;
    #pragma unroll
    for (int it = 0; it < 2; ++it) {
      int c0 = wid * 8 + it * 48;
      bf16x8 pk;
      #pragma unroll
      for (int j = 0; j < 8; ++j)
        pk[j] = (bf16)x[(size_t)(b * 768 + cbase + c0 + j) * 4096 + s0 + l];
      *(bf16x8*)(ldsT + ((l * 256 + c0 * 2) ^ ((l & 7) << 4))) = pk;
    }
    __syncthreads();
    #pragma unroll
    for (int kk = 0; kk < 3; ++kk) {
      bf16x8 af[3], bv[4];
      #pragma unroll
      for (int ma = 0; ma < 3; ++ma) {
        int row = wid * 48 + ma * 16 + lr;
        af[ma] = *(const bf16x8*)&Wqkv[(size_t)row * 768 + cbase + kk * 32 + lq * 8];
      }
      #pragma unroll
      for (int nb = 0; nb < 4; ++nb) {
        int sl = nb * 16 + lr;
        bv[nb] = *(const bf16x8*)(ldsT + ((sl * 256 + (kk * 32 + lq * 8) * 2) ^ ((sl & 7) << 4)));
      }
      #pragma unroll
      for (int ma = 0; ma < 3; ++ma)
        #pragma unroll
        for (int nb = 0; nb < 4; ++nb)
          acc[ma][nb] = MFMA16(af[ma], bv[nb], acc[ma][nb]);
    }
    __syncthreads();
  }
  #pragma unroll
  for (int ma = 0; ma < 3; ++ma)
    #pragma unroll
    for (int nb = 0; nb < 4; ++nb)
      #pragma unroll
      for (int i = 0; i < 4; ++i) {
        int o3 = wid * 48 + ma * 16 + lq * 4 + i;
        int s  = s0 + nb * 16 + lr;
        QKV[((size_t)b * 288 + o3) * 4096 + s] = (bf16)acc[ma][nb][i];
      }
}

// ---------------- k1b: transpose V -> Vt[b][64 w][6144 l] ----------------
__global__ __launch_bounds__(256) void k_vt(const bf16* __restrict__ QKV,
                                            bf16* __restrict__ Vt) {
  __shared__ __align__(16) unsigned char T[64 * 128];
  const int t = threadIdx.x;
  const int b = blockIdx.y, ck = blockIdx.x;
  const bf16* Vb = QKV + (size_t)b * 288 * 4096 + (size_t)192 * 4096 + (size_t)ck * 4096;
  #pragma unroll
  for (int it = 0; it < 2; ++it) {
    int h = (t >> 3) + it * 32;
    int c8 = t & 7;
    u16x8 v = *(const u16x8*)&Vb[h * 64 + c8 * 8];
    *(u16x8*)(T + ((h * 128 + c8 * 16) ^ ((h & 7) << 4))) = v;
  }
  __syncthreads();
  const int w = t & 63, hs = t >> 6;
  u16x8 o0, o1;
  #pragma unroll
  for (int e = 0; e < 8; ++e) {
    int h = hs * 16 + e;
    o0[e] = *(const unsigned short*)(T + ((h * 128 + w * 2) ^ ((h & 7) << 4)));
  }
  #pragma unroll
  for (int e = 0; e < 8; ++e) {
    int h = hs * 16 + 8 + e;
    o1[e] = *(const unsigned short*)(T + ((h * 128 + w * 2) ^ ((h & 7) << 4)));
  }
  bf16* dst = Vt + (size_t)b * 64 * 6144 + (size_t)w * 6144 + ck * 64 + hs * 16;
  *(u16x8*)(dst) = o0;
  *(u16x8*)(dst + 8) = o1;
}

// ---------------- k2: attention, no-max softmax + KV-split x2 ----------------
// grid (96, 2, 8): qb, split, batch. 4 waves x 16 q-rows. log2e folded into Q.
// Writes unnormalized partial O (bf16) + partial row-sums (f32); no cross-lane
// ops and no rescale inside the loop -> fully pipelineable, 6 blocks/CU.
__global__ __launch_bounds__(256, 6) void k_attn(bf16* qkv,
                                                 const bf16* __restrict__ Vt,
                                                 bf16* __restrict__ Op0,
                                                 float* __restrict__ L) {
  __shared__ __align__(16) unsigned char Pl[4][2048];   // [kk][lane][16B] per wave
  const int t = threadIdx.x, wid = t >> 6, l = t & 63;
  const int qb = blockIdx.x, sp = blockIdx.y, b = blockIdx.z;
  const int lq = l >> 4, lr = l & 15;
  const bf16* Qb  = qkv + (size_t)b * 288 * 4096;
  const bf16* Kb  = Qb + (size_t)96 * 4096;
  const bf16* Vtb = Vt + (size_t)b * 64 * 6144;
  const int qr = qb * 64 + wid * 16 + lr;
  const float LOG2E = 1.44269504f;
  bf16x8 qf[2];
  {
    bf16x8 q0 = *(const bf16x8*)&Qb[(size_t)qr * 64 + lq * 8];
    bf16x8 q1 = *(const bf16x8*)&Qb[(size_t)qr * 64 + 32 + lq * 8];
    #pragma unroll
    for (int e = 0; e < 8; ++e) {
      qf[0][e] = (bf16)((float)q0[e] * LOG2E);
      qf[1][e] = (bf16)((float)q1[e] * LOG2E);
    }
  }
  f32x4 oacc[4] = {};
  float lacc = 0.f;
  unsigned char* Pw = Pl[wid];
  const int pwb = lr * 16 + (lq & 1) * 8 + (lq >> 1) * 256;  // P write base (A-frag order)
  const int kt0 = sp * 48;

  for (int kt = kt0; kt < kt0 + 48; ++kt) {
    const bf16* Kt = Kb + (size_t)kt * 64 * 64;
    // V first-half loads early (covered by QK^T + exp)
    bf16x8 vf0[4];
    #pragma unroll
    for (int wb = 0; wb < 4; ++wb)
      vf0[wb] = *(const bf16x8*)&Vtb[(size_t)(wb * 16 + lr) * 6144 + kt * 64 + lq * 8];
    // QK^T (S^T): lane -> q-row lr, kcols kb*16 + lq*4 + i  (already in base-2 units)
    f32x4 st[4] = {};
    #pragma unroll
    for (int kb = 0; kb < 4; ++kb) {
      bf16x8 k0 = *(const bf16x8*)&Kt[(size_t)(kb * 16 + lr) * 64 + lq * 8];
      bf16x8 k1 = *(const bf16x8*)&Kt[(size_t)(kb * 16 + lr) * 64 + 32 + lq * 8];
      st[kb] = MFMA16(k0, qf[0], st[kb]);
      st[kb] = MFMA16(k1, qf[1], st[kb]);
    }
    bf16x8 vf1[4];
    #pragma unroll
    for (int wb = 0; wb < 4; ++wb)
      vf1[wb] = *(const bf16x8*)&Vtb[(size_t)(wb * 16 + lr) * 6144 + kt * 64 + 32 + lq * 8];
    // phase A: kcols 0..31 (kb 0,1) -> LDS -> PV with vf0
    #pragma unroll
    for (int kb = 0; kb < 2; ++kb)
      #pragma unroll
      for (int pr = 0; pr < 2; ++pr) {
        float p0 = exp2f(st[kb][pr * 2]);
        float p1 = exp2f(st[kb][pr * 2 + 1]);
        lacc += p0 + p1;
        bf16 b0 = (bf16)p0, b1 = (bf16)p1;
        unsigned int u = (unsigned int)__builtin_bit_cast(unsigned short, b0)
                       | ((unsigned int)__builtin_bit_cast(unsigned short, b1) << 16);
        *(unsigned int*)(Pw + pwb + kb * 512 + pr * 4) = u;
      }
    {
      bf16x8 pa = *(const bf16x8*)(Pw + l * 16);
      #pragma unroll
      for (int wb = 0; wb < 4; ++wb)
        oacc[wb] = MFMA16(pa, vf0[wb], oacc[wb]);
    }
    // phase B: kcols 32..63 (kb 2,3) -> LDS -> PV with vf1
    #pragma unroll
    for (int kb = 2; kb < 4; ++kb)
      #pragma unroll
      for (int pr = 0; pr < 2; ++pr) {
        float p0 = exp2f(st[kb][pr * 2]);
        float p1 = exp2f(st[kb][pr * 2 + 1]);
        lacc += p0 + p1;
        bf16 b0 = (bf16)p0, b1 = (bf16)p1;
        unsigned int u = (unsigned int)__builtin_bit_cast(unsigned short, b0)
                       | ((unsigned int)__builtin_bit_cast(unsigned short, b1) << 16);
        *(unsigned int*)(Pw + pwb + (kb - 2) * 512 + 1024 + pr * 4) = u;
      }
    {
      bf16x8 pa = *(const bf16x8*)(Pw + 1024 + l * 16);
      #pragma unroll
      for (int wb = 0; wb < 4; ++wb)
        oacc[wb] = MFMA16(pa, vf1[wb], oacc[wb]);
    }
  }
  // partial row-sum: sum over the 4 lq lanes holding row lr
  float rs = lacc;
  rs += __shfl_xor(rs, 16);
  rs += __shfl_xor(rs, 32);
  if (lq == 0)
    L[(size_t)sp * 49152 + (size_t)b * 6144 + qb * 64 + wid * 16 + lr] = rs;
  // unnormalized partial O (bf16): split 0 -> Op0, split 1 -> dead V region
  bf16* Ob = sp ? (qkv + ((size_t)b * 288 + 192) * 4096)
              : (Op0 + (size_t)b * 96 * 4096);
  #pragma unroll
  for (int wb = 0; wb < 4; ++wb)
    #pragma unroll
    for (int i = 0; i < 4; ++i) {
      int row = qb * 64 + wid * 16 + lq * 4 + i;
      Ob[(size_t)row * 64 + wb * 16 + lr] = (bf16)oacc[wb][i];
    }
}

// ---------------- k2b: combine splits + normalize + transpose -> At ----------------
// block (s-block=h, b). Op0 layout == A[b][96][4096]; Op1 in V region; At -> Q region.
__global__ __launch_bounds__(256) void k_fin(bf16* qkv,
                                             const bf16* __restrict__ Op0,
                                             const float* __restrict__ L) {
  __shared__ unsigned char T[96 * 128];
  const int t = threadIdx.x;
  const int b = blockIdx.y, bx = blockIdx.x, s0 = bx * 64;
  const bf16* Op1 = qkv + ((size_t)b * 288 + 192) * 4096;
  #pragma unroll
  for (int it = 0; it < 6; ++it) {
    int c = (t >> 4) + it * 16;
    int s = (t & 15) * 4;
    int row = c * 64 + bx;
    float linv = 1.0f / (L[(size_t)b * 6144 + row] + L[49152 + (size_t)b * 6144 + row]);
    u16x4 va0 = *(const u16x4*)&Op0[((size_t)b * 96 + c) * 4096 + s0 + s];
    u16x4 va1 = *(const u16x4*)&Op1[(size_t)c * 4096 + s0 + s];
    float f[4];
    #pragma unroll
    for (int e = 0; e < 4; ++e) {
      float x0 = __builtin_bit_cast(float, ((unsigned int)va0[e]) << 16);
      float x1 = __builtin_bit_cast(float, ((unsigned int)va1[e]) << 16);
      f[e] = (x0 + x1) * linv;
    }
    #pragma unroll
    for (int pr = 0; pr < 2; ++pr) {
      bf16 b0 = (bf16)f[pr * 2], b1 = (bf16)f[pr * 2 + 1];
      unsigned int u = (unsigned int)__builtin_bit_cast(unsigned short, b0)
                     | ((unsigned int)__builtin_bit_cast(unsigned short, b1) << 16);
      int byte = (c * 128 + (s + pr * 2) * 2) ^ ((c & 7) << 2) ^ (((c >> 3) & 3) << 5);
      *(unsigned int*)(T + byte) = u;
    }
  }
  __syncthreads();
  int s = t >> 2, c0 = (t & 3) * 24;
  unsigned short us[24];
  #pragma unroll
  for (int e = 0; e < 24; ++e) {
    int c = c0 + e;
    int byte = (c * 128 + s * 2) ^ ((c & 7) << 2) ^ (((c >> 3) & 3) << 5);
    us[e] = *(const unsigned short*)(T + byte);
  }
  bf16* dst = qkv + (size_t)b * 288 * 4096 + (size_t)(s0 + s) * 96 + c0;
  #pragma unroll
  for (int v8 = 0; v8 < 3; ++v8) {
    u16x8 o;
    #pragma unroll
    for (int e = 0; e < 8; ++e) o[e] = us[v8 * 8 + e];
    *(u16x8*)(dst + v8 * 8) = o;
  }
}

// ---------------- k3: out = gamma * (Wc @ A) + x ----------------
__global__ __launch_bounds__(256) void k_out(const float* __restrict__ x,
                                             const bf16* __restrict__ Wcb,
                                             const bf16* __restrict__ At,
                                             const float* __restrict__ gamma,
                                             float* __restrict__ out) {
  const int t = threadIdx.x, wid = t >> 6, l = t & 63;
  const int lq = l >> 4, lr = l & 15;
  const int b = blockIdx.z, mb = blockIdx.y, s0 = blockIdx.x * 64;
  f32x4 acc[4][4] = {};
  #pragma unroll
  for (int kk = 0; kk < 3; ++kk) {
    bf16x8 af[4], bv[4];
    #pragma unroll
    for (int ma = 0; ma < 4; ++ma) {
      int row = mb * 256 + wid * 64 + ma * 16 + lr;
      af[ma] = *(const bf16x8*)&Wcb[(size_t)row * 96 + kk * 32 + lq * 8];
    }
    #pragma unroll
    for (int nb = 0; nb < 4; ++nb) {
      int s = s0 + nb * 16 + lr;
      bv[nb] = *(const bf16x8*)&At[(size_t)b * 288 * 4096 + (size_t)s * 96 + kk * 32 + lq * 8];
    }
    #pragma unroll
    for (int ma = 0; ma < 4; ++ma)
      #pragma unroll
      for (int nb = 0; nb < 4; ++nb)
        acc[ma][nb] = MFMA16(af[ma], bv[nb], acc[ma][nb]);
  }
  float g = gamma[0];
  #pragma unroll
  for (int ma = 0; ma < 4; ++ma)
    #pragma unroll
    for (int nb = 0; nb < 4; ++nb)
      #pragma unroll
      for (int i = 0; i < 4; ++i) {
        int o2 = mb * 256 + wid * 64 + ma * 16 + lq * 4 + i;
        int s  = s0 + nb * 16 + lr;
        size_t idx = ((size_t)b * 768 + o2) * 4096 + s;
        out[idx] = fmaf(acc[ma][nb][i], g, x[idx]);
      }
}

extern "C" void kernel_launch(void* const* d_in, const int* in_sizes, int n_in,
                              void* d_out, int out_size, void* d_ws, size_t ws_size,
                              hipStream_t stream) {
  (void)in_sizes; (void)n_in; (void)out_size; (void)ws_size;
  const float* x     = (const float*)d_in[0];
  const float* Wq    = (const float*)d_in[1];
  const float* Wk    = (const float*)d_in[2];
  const float* Wv    = (const float*)d_in[3];
  const float* Wc    = (const float*)d_in[4];
  const float* gamma = (const float*)d_in[5];
  float* out = (float*)d_out;
  char* ws = (char*)d_ws;
  bf16*  Wqkv = (bf16*)(ws + OFF_WQKV);
  bf16*  Wcb  = (bf16*)(ws + OFF_WC);
  bf16*  QKV  = (bf16*)(ws + OFF_QKV);
  bf16*  Op0  = (bf16*)(ws + OFF_A);
  bf16*  Vt   = (bf16*)(ws + OFF_AT);
  float* Lsum = (float*)(ws + OFF_WQKV);   // overlays dead proj weights

  k_wcvt<<<dim3(288), dim3(256), 0, stream>>>(Wq, Wk, Wv, Wc, Wqkv, Wcb);
  k_proj<<<dim3(64, 8), dim3(384), 0, stream>>>(x, Wqkv, QKV);
  k_vt<<<dim3(96, 8), dim3(256), 0, stream>>>(QKV, Vt);
  k_attn<<<dim3(96, 2, 8), dim3(256), 0, stream>>>(QKV, Vt, Op0, Lsum);
  k_fin<<<dim3(64, 8), dim3(256), 0, stream>>>(QKV, Op0, Lsum);
  k_out<<<dim3(64, 3, 8), dim3(256), 0, stream>>>(x, Wcb, QKV, gamma, out);
}

// Round 5
// 391.782 us; speedup vs baseline: 1.9555x; 1.9533x over previous
//
#include <hip/hip_runtime.h>

typedef __bf16 bf16;
typedef __attribute__((ext_vector_type(8))) __bf16 bf16x8;
typedef __attribute__((ext_vector_type(4))) float f32x4;
typedef __attribute__((ext_vector_type(4))) unsigned short u16x4;
typedef __attribute__((ext_vector_type(8))) unsigned short u16x8;
typedef __attribute__((ext_vector_type(4))) float float4v;

#define MFMA16(a,b,c) __builtin_amdgcn_mfma_f32_16x16x32_bf16((a),(b),(c),0,0,0)

// Problem dims: B=8, C=768, H=W=64, S=4096, CK=96, L=CK*H=6144, D=W=64
// Workspace layout (bytes), peak 32.1 MB with region reuse:
//   OFF_WQKV: [288][768] bf16 proj weights; dead after k_proj -> Lsum[2][8][6144] f32
//   OFF_WC:   [768][96] bf16 (live to the end)
//   OFF_QKV:  [8][288][4096] bf16. Per batch: rows 0-95=Q, 96-191=K, 192-287=V.
//             V region dead after k_vt   -> Opart1[b][6144][64] bf16
//             Q region dead after k_attn -> At[b][4096][96] bf16
//   OFF_A:    [8][96][4096] bf16 = Opart0
//   OFF_AT:   Vt[8][64][6144] bf16
static constexpr size_t OFF_WQKV = 0;
static constexpr size_t OFF_WC   = OFF_WQKV + (size_t)288*768*2;
static constexpr size_t OFF_QKV  = OFF_WC   + (size_t)768*96*2;
static constexpr size_t OFF_A    = OFF_QKV  + (size_t)8*288*4096*2;
static constexpr size_t OFF_AT   = OFF_A    + (size_t)8*96*4096*2;

// ---------------- k0: convert weights to bf16 ----------------
__global__ __launch_bounds__(256) void k_wcvt(const float* __restrict__ Wq,
                                              const float* __restrict__ Wk,
                                              const float* __restrict__ Wv,
                                              const float* __restrict__ Wc,
                                              bf16* __restrict__ Wqkv,
                                              bf16* __restrict__ Wcb) {
  int t = blockIdx.x * 256 + threadIdx.x;
  int base = t * 4;
  float4v v;
  if (base < 73728)        v = ((const float4v*)Wq)[t];
  else if (base < 147456)  v = ((const float4v*)Wk)[t - 18432];
  else if (base < 221184)  v = ((const float4v*)Wv)[t - 36864];
  else                     v = ((const float4v*)Wc)[t - 55296];
  u16x4 o;
  #pragma unroll
  for (int i = 0; i < 4; ++i) {
    bf16 h = (bf16)v[i];
    o[i] = __builtin_bit_cast(unsigned short, h);
  }
  if (base < 221184) ((u16x4*)Wqkv)[t] = o;
  else               ((u16x4*)Wcb)[t - 55296] = o;
}

// ---------------- k1: fused QKV projection ----------------
__global__ __launch_bounds__(384) void k_proj(const float* __restrict__ x,
                                              const bf16* __restrict__ Wqkv,
                                              bf16* __restrict__ QKV) {
  __shared__ __align__(16) unsigned char ldsT[64 * 256];
  const int t = threadIdx.x, wid = t >> 6, l = t & 63;
  const int b = blockIdx.y, s0 = blockIdx.x * 64;
  const int lq = l >> 4, lr = l & 15;
  f32x4 acc[3][4] = {};
  for (int ch = 0; ch < 8; ++ch) {
    const int cbase = ch * 96;
    #pragma unroll
    for (int it = 0; it < 2; ++it) {
      int c0 = wid * 8 + it * 48;
      bf16x8 pk;
      #pragma unroll
      for (int j = 0; j < 8; ++j)
        pk[j] = (bf16)x[(size_t)(b * 768 + cbase + c0 + j) * 4096 + s0 + l];
      *(bf16x8*)(ldsT + ((l * 256 + c0 * 2) ^ ((l & 7) << 4))) = pk;
    }
    __syncthreads();
    #pragma unroll
    for (int kk = 0; kk < 3; ++kk) {
      bf16x8 af[3], bv[4];
      #pragma unroll
      for (int ma = 0; ma < 3; ++ma) {
        int row = wid * 48 + ma * 16 + lr;
        af[ma] = *(const bf16x8*)&Wqkv[(size_t)row * 768 + cbase + kk * 32 + lq * 8];
      }
      #pragma unroll
      for (int nb = 0; nb < 4; ++nb) {
        int sl = nb * 16 + lr;
        bv[nb] = *(const bf16x8*)(ldsT + ((sl * 256 + (kk * 32 + lq * 8) * 2) ^ ((sl & 7) << 4)));
      }
      #pragma unroll
      for (int ma = 0; ma < 3; ++ma)
        #pragma unroll
        for (int nb = 0; nb < 4; ++nb)
          acc[ma][nb] = MFMA16(af[ma], bv[nb], acc[ma][nb]);
    }
    __syncthreads();
  }
  #pragma unroll
  for (int ma = 0; ma < 3; ++ma)
    #pragma unroll
    for (int nb = 0; nb < 4; ++nb)
      #pragma unroll
      for (int i = 0; i < 4; ++i) {
        int o3 = wid * 48 + ma * 16 + lq * 4 + i;
        int s  = s0 + nb * 16 + lr;
        QKV[((size_t)b * 288 + o3) * 4096 + s] = (bf16)acc[ma][nb][i];
      }
}

// ---------------- k1b: transpose V -> Vt[b][64 w][6144 l] ----------------
__global__ __launch_bounds__(256) void k_vt(const bf16* __restrict__ QKV,
                                            bf16* __restrict__ Vt) {
  __shared__ __align__(16) unsigned char T[64 * 128];
  const int t = threadIdx.x;
  const int b = blockIdx.y, ck = blockIdx.x;
  const bf16* Vb = QKV + (size_t)b * 288 * 4096 + (size_t)192 * 4096 + (size_t)ck * 4096;
  #pragma unroll
  for (int it = 0; it < 2; ++it) {
    int h = (t >> 3) + it * 32;
    int c8 = t & 7;
    u16x8 v = *(const u16x8*)&Vb[h * 64 + c8 * 8];
    *(u16x8*)(T + ((h * 128 + c8 * 16) ^ ((h & 7) << 4))) = v;
  }
  __syncthreads();
  const int w = t & 63, hs = t >> 6;
  u16x8 o0, o1;
  #pragma unroll
  for (int e = 0; e < 8; ++e) {
    int h = hs * 16 + e;
    o0[e] = *(const unsigned short*)(T + ((h * 128 + w * 2) ^ ((h & 7) << 4)));
  }
  #pragma unroll
  for (int e = 0; e < 8; ++e) {
    int h = hs * 16 + 8 + e;
    o1[e] = *(const unsigned short*)(T + ((h * 128 + w * 2) ^ ((h & 7) << 4)));
  }
  bf16* dst = Vt + (size_t)b * 64 * 6144 + (size_t)w * 6144 + ck * 64 + hs * 16;
  *(u16x8*)(dst) = o0;
  *(u16x8*)(dst + 8) = o1;
}

// ---------------- k2: attention, LDS-staged K/V + XCD-pinned batches ----------------
// 1-D grid 1536: b = id&7 (-> XCD via round-robin), r=id>>3: qb=r>>1, sp=r&1.
// K,V tiles staged once per block via global_load_lds (linear dest, swizzled src),
// shared by 4 waves. No-max softmax (log2e folded into Q), KV-split x2.
__global__ __launch_bounds__(256, 6) void k_attn(bf16* qkv,
                                                 const bf16* __restrict__ Vt,
                                                 bf16* __restrict__ Op0,
                                                 float* __restrict__ L) {
  __shared__ __align__(16) unsigned char Kl[8192];      // K tile [64 kv][64 d], swz ^((row&7)<<4)
  __shared__ __align__(16) unsigned char Vl[8192];      // V^T tile [64 w][64 kv], same swz
  __shared__ __align__(16) unsigned char Pl[4][2048];   // per-wave P in A-frag order
  const int t = threadIdx.x, wid = t >> 6, l = t & 63;
  const int id = blockIdx.x;
  const int b = id & 7, r = id >> 3, qb = r >> 1, sp = r & 1;
  const int lq = l >> 4, lr = l & 15;
  const bf16* Qb  = qkv + (size_t)b * 288 * 4096;
  const char* Kbase = (const char*)(Qb + (size_t)96 * 4096);
  const char* Vtbase = (const char*)(Vt + (size_t)b * 64 * 6144);
  const int qr = qb * 64 + wid * 16 + lr;
  const float LOG2E = 1.44269504f;
  bf16x8 qf[2];
  {
    bf16x8 q0 = *(const bf16x8*)&Qb[(size_t)qr * 64 + lq * 8];
    bf16x8 q1 = *(const bf16x8*)&Qb[(size_t)qr * 64 + 32 + lq * 8];
    #pragma unroll
    for (int e = 0; e < 8; ++e) {
      qf[0][e] = (bf16)((float)q0[e] * LOG2E);
      qf[1][e] = (bf16)((float)q1[e] * LOG2E);
    }
  }
  f32x4 oacc[4] = {};
  float lacc = 0.f;
  unsigned char* Pw = Pl[wid];
  const int pwb = lr * 16 + (lq & 1) * 8 + (lq >> 1) * 256;  // P write base (A-frag order)
  // per-lane staged-source swizzle offsets (two 1KB segments per wave, K and V)
  const int soff0 = wid * 2048 + l * 16;
  const int soff1 = soff0 + 1024;
  const int row0 = soff0 >> 7, scol0 = (soff0 & 127) ^ ((row0 & 7) << 4);
  const int row1 = soff1 >> 7, scol1 = (soff1 & 127) ^ ((row1 & 7) << 4);
  const int kt0 = sp * 48;

  for (int kt = kt0; kt < kt0 + 48; ++kt) {
    // ---- stage K tile (contiguous 8KB) and V^T tile (64 rows x 128B) ----
    {
      const char* ksrc = Kbase + (size_t)kt * 8192;
      const char* vsrc = Vtbase + (size_t)kt * 128;
      __builtin_amdgcn_global_load_lds(
        (const __attribute__((address_space(1))) void*)(ksrc + row0 * 128 + scol0),
        (__attribute__((address_space(3))) void*)(Kl + wid * 2048), 16, 0, 0);
      __builtin_amdgcn_global_load_lds(
        (const __attribute__((address_space(1))) void*)(ksrc + row1 * 128 + scol1),
        (__attribute__((address_space(3))) void*)(Kl + wid * 2048 + 1024), 16, 0, 0);
      __builtin_amdgcn_global_load_lds(
        (const __attribute__((address_space(1))) void*)(vsrc + (size_t)row0 * 12288 + scol0),
        (__attribute__((address_space(3))) void*)(Vl + wid * 2048), 16, 0, 0);
      __builtin_amdgcn_global_load_lds(
        (const __attribute__((address_space(1))) void*)(vsrc + (size_t)row1 * 12288 + scol1),
        (__attribute__((address_space(3))) void*)(Vl + wid * 2048 + 1024), 16, 0, 0);
    }
    __syncthreads();   // staged data visible (implicit vmcnt(0) drain)
    // ---- QK^T from LDS: lane -> q-row lr, kcols kb*16 + lq*4 + i ----
    f32x4 st[4] = {};
    #pragma unroll
    for (int kb = 0; kb < 4; ++kb) {
      int rr = kb * 16 + lr;
      bf16x8 k0 = *(const bf16x8*)(Kl + rr * 128 + ((lq * 16) ^ ((rr & 7) << 4)));
      bf16x8 k1 = *(const bf16x8*)(Kl + rr * 128 + ((64 + lq * 16) ^ ((rr & 7) << 4)));
      st[kb] = MFMA16(k0, qf[0], st[kb]);
      st[kb] = MFMA16(k1, qf[1], st[kb]);
    }
    // ---- phase A: kcols 0..31 -> P -> PV (V kv-cols 0..31) ----
    #pragma unroll
    for (int kb = 0; kb < 2; ++kb)
      #pragma unroll
      for (int pr = 0; pr < 2; ++pr) {
        float p0 = exp2f(st[kb][pr * 2]);
        float p1 = exp2f(st[kb][pr * 2 + 1]);
        lacc += p0 + p1;
        bf16 b0 = (bf16)p0, b1 = (bf16)p1;
        unsigned int u = (unsigned int)__builtin_bit_cast(unsigned short, b0)
                       | ((unsigned int)__builtin_bit_cast(unsigned short, b1) << 16);
        *(unsigned int*)(Pw + pwb + kb * 512 + pr * 4) = u;
      }
    {
      bf16x8 pa = *(const bf16x8*)(Pw + l * 16);
      #pragma unroll
      for (int wb = 0; wb < 4; ++wb) {
        int w = wb * 16 + lr;
        bf16x8 vv = *(const bf16x8*)(Vl + w * 128 + ((lq * 16) ^ ((w & 7) << 4)));
        oacc[wb] = MFMA16(pa, vv, oacc[wb]);
      }
    }
    // ---- phase B: kcols 32..63 -> P -> PV (V kv-cols 32..63) ----
    #pragma unroll
    for (int kb = 2; kb < 4; ++kb)
      #pragma unroll
      for (int pr = 0; pr < 2; ++pr) {
        float p0 = exp2f(st[kb][pr * 2]);
        float p1 = exp2f(st[kb][pr * 2 + 1]);
        lacc += p0 + p1;
        bf16 b0 = (bf16)p0, b1 = (bf16)p1;
        unsigned int u = (unsigned int)__builtin_bit_cast(unsigned short, b0)
                       | ((unsigned int)__builtin_bit_cast(unsigned short, b1) << 16);
        *(unsigned int*)(Pw + pwb + (kb - 2) * 512 + 1024 + pr * 4) = u;
      }
    {
      bf16x8 pa = *(const bf16x8*)(Pw + 1024 + l * 16);
      #pragma unroll
      for (int wb = 0; wb < 4; ++wb) {
        int w = wb * 16 + lr;
        bf16x8 vv = *(const bf16x8*)(Vl + w * 128 + ((64 + lq * 16) ^ ((w & 7) << 4)));
        oacc[wb] = MFMA16(pa, vv, oacc[wb]);
      }
    }
    __syncthreads();   // all waves done reading before next stage overwrites
  }
  // partial row-sum over the 4 lq lanes holding row lr
  float rs = lacc;
  rs += __shfl_xor(rs, 16);
  rs += __shfl_xor(rs, 32);
  if (lq == 0)
    L[(size_t)sp * 49152 + (size_t)b * 6144 + qb * 64 + wid * 16 + lr] = rs;
  // unnormalized partial O (bf16): split 0 -> Op0, split 1 -> dead V region
  bf16* Ob = sp ? (qkv + ((size_t)b * 288 + 192) * 4096)
              : (Op0 + (size_t)b * 96 * 4096);
  #pragma unroll
  for (int wb = 0; wb < 4; ++wb)
    #pragma unroll
    for (int i = 0; i < 4; ++i) {
      int row = qb * 64 + wid * 16 + lq * 4 + i;
      Ob[(size_t)row * 64 + wb * 16 + lr] = (bf16)oacc[wb][i];
    }
}

// ---------------- k2b: combine splits + normalize + transpose -> At ----------------
__global__ __launch_bounds__(256) void k_fin(bf16* qkv,
                                             const bf16* __restrict__ Op0,
                                             const float* __restrict__ L) {
  __shared__ unsigned char T[96 * 128];
  const int t = threadIdx.x;
  const int b = blockIdx.y, bx = blockIdx.x, s0 = bx * 64;
  const bf16* Op1 = qkv + ((size_t)b * 288 + 192) * 4096;
  #pragma unroll
  for (int it = 0; it < 6; ++it) {
    int c = (t >> 4) + it * 16;
    int s = (t & 15) * 4;
    int row = c * 64 + bx;
    float linv = 1.0f / (L[(size_t)b * 6144 + row] + L[49152 + (size_t)b * 6144 + row]);
    u16x4 va0 = *(const u16x4*)&Op0[((size_t)b * 96 + c) * 4096 + s0 + s];
    u16x4 va1 = *(const u16x4*)&Op1[(size_t)c * 4096 + s0 + s];
    float f[4];
    #pragma unroll
    for (int e = 0; e < 4; ++e) {
      float x0 = __builtin_bit_cast(float, ((unsigned int)va0[e]) << 16);
      float x1 = __builtin_bit_cast(float, ((unsigned int)va1[e]) << 16);
      f[e] = (x0 + x1) * linv;
    }
    #pragma unroll
    for (int pr = 0; pr < 2; ++pr) {
      bf16 b0 = (bf16)f[pr * 2], b1 = (bf16)f[pr * 2 + 1];
      unsigned int u = (unsigned int)__builtin_bit_cast(unsigned short, b0)
                     | ((unsigned int)__builtin_bit_cast(unsigned short, b1) << 16);
      int byte = (c * 128 + (s + pr * 2) * 2) ^ ((c & 7) << 2) ^ (((c >> 3) & 3) << 5);
      *(unsigned int*)(T + byte) = u;
    }
  }
  __syncthreads();
  int s = t >> 2, c0 = (t & 3) * 24;
  unsigned short us[24];
  #pragma unroll
  for (int e = 0; e < 24; ++e) {
    int c = c0 + e;
    int byte = (c * 128 + s * 2) ^ ((c & 7) << 2) ^ (((c >> 3) & 3) << 5);
    us[e] = *(const unsigned short*)(T + byte);
  }
  bf16* dst = qkv + (size_t)b * 288 * 4096 + (size_t)(s0 + s) * 96 + c0;
  #pragma unroll
  for (int v8 = 0; v8 < 3; ++v8) {
    u16x8 o;
    #pragma unroll
    for (int e = 0; e < 8; ++e) o[e] = us[v8 * 8 + e];
    *(u16x8*)(dst + v8 * 8) = o;
  }
}

// ---------------- k3: out = gamma * (Wc @ A) + x ----------------
__global__ __launch_bounds__(256) void k_out(const float* __restrict__ x,
                                             const bf16* __restrict__ Wcb,
                                             const bf16* __restrict__ At,
                                             const float* __restrict__ gamma,
                                             float* __restrict__ out) {
  const int t = threadIdx.x, wid = t >> 6, l = t & 63;
  const int lq = l >> 4, lr = l & 15;
  const int b = blockIdx.z, mb = blockIdx.y, s0 = blockIdx.x * 64;
  f32x4 acc[4][4] = {};
  #pragma unroll
  for (int kk = 0; kk < 3; ++kk) {
    bf16x8 af[4], bv[4];
    #pragma unroll
    for (int ma = 0; ma < 4; ++ma) {
      int row = mb * 256 + wid * 64 + ma * 16 + lr;
      af[ma] = *(const bf16x8*)&Wcb[(size_t)row * 96 + kk * 32 + lq * 8];
    }
    #pragma unroll
    for (int nb = 0; nb < 4; ++nb) {
      int s = s0 + nb * 16 + lr;
      bv[nb] = *(const bf16x8*)&At[(size_t)b * 288 * 4096 + (size_t)s * 96 + kk * 32 + lq * 8];
    }
    #pragma unroll
    for (int ma = 0; ma < 4; ++ma)
      #pragma unroll
      for (int nb = 0; nb < 4; ++nb)
        acc[ma][nb] = MFMA16(af[ma], bv[nb], acc[ma][nb]);
  }
  float g = gamma[0];
  #pragma unroll
  for (int ma = 0; ma < 4; ++ma)
    #pragma unroll
    for (int nb = 0; nb < 4; ++nb)
      #pragma unroll
      for (int i = 0; i < 4; ++i) {
        int o2 = mb * 256 + wid * 64 + ma * 16 + lq * 4 + i;
        int s  = s0 + nb * 16 + lr;
        size_t idx = ((size_t)b * 768 + o2) * 4096 + s;
        out[idx] = fmaf(acc[ma][nb][i], g, x[idx]);
      }
}

extern "C" void kernel_launch(void* const* d_in, const int* in_sizes, int n_in,
                              void* d_out, int out_size, void* d_ws, size_t ws_size,
                              hipStream_t stream) {
  (void)in_sizes; (void)n_in; (void)out_size; (void)ws_size;
  const float* x     = (const float*)d_in[0];
  const float* Wq    = (const float*)d_in[1];
  const float* Wk    = (const float*)d_in[2];
  const float* Wv    = (const float*)d_in[3];
  const float* Wc    = (const float*)d_in[4];
  const float* gamma = (const float*)d_in[5];
  float* out = (float*)d_out;
  char* ws = (char*)d_ws;
  bf16*  Wqkv = (bf16*)(ws + OFF_WQKV);
  bf16*  Wcb  = (bf16*)(ws + OFF_WC);
  bf16*  QKV  = (bf16*)(ws + OFF_QKV);
  bf16*  Op0  = (bf16*)(ws + OFF_A);
  bf16*  Vt   = (bf16*)(ws + OFF_AT);
  float* Lsum = (float*)(ws + OFF_WQKV);   // overlays dead proj weights

  k_wcvt<<<dim3(288), dim3(256), 0, stream>>>(Wq, Wk, Wv, Wc, Wqkv, Wcb);
  k_proj<<<dim3(64, 8), dim3(384), 0, stream>>>(x, Wqkv, QKV);
  k_vt<<<dim3(96, 8), dim3(256), 0, stream>>>(QKV, Vt);
  k_attn<<<dim3(1536), dim3(256), 0, stream>>>(QKV, Vt, Op0, Lsum);
  k_fin<<<dim3(64, 8), dim3(256), 0, stream>>>(QKV, Op0, Lsum);
  k_out<<<dim3(64, 3, 8), dim3(256), 0, stream>>>(x, Wcb, QKV, gamma, out);
}